// Round 5
// baseline (144.510 us; speedup 1.0000x reference)
//
#include <hip/hip_runtime.h>
#include <hip/hip_bf16.h>

// Batched matmul: [24,1024,64] fp32 x [24,64,1024] fp32 -> [24,1024,1024] fp32.
// R10: MEASUREMENT + dwordx4 epilogue probe.
//   Fact base: R6/R8/R9 (scalar-store GEMMs, 3 different tilings, nt vs cached)
//   are all 122 +/- 0.5us -> store locality/mode innocent. Remaining ambiguity:
//   bmm duration B is unobservable (top-5 = harness fills only). This round:
//   (a) epilogue upgraded to 16B/lane global_store_dwordx4 via per-wave LDS
//       transpose (every observed >=6TB/s writer uses 16B/lane; our 4B/lane
//       scalar stores never exceeded ~2.2TB/s effective),
//   (b) bmm launched TWICE (duplicate writes disjoint ws region) so
//       dur = F + reformat + 2*B_new, separating fixed-floor vs slow-store
//       hypotheses in one bench.
// LDS transpose is bit-exact pass-through -> absmax unchanged (0.25).

#define NN 1024

typedef __attribute__((ext_vector_type(4))) float  float4v;
typedef __attribute__((ext_vector_type(8))) short  bf16x8;    // 8 bf16 = 16 B
typedef __attribute__((ext_vector_type(16))) float floatx16;  // 32x32 MFMA acc

// fp32 -> bf16 bits, round-to-nearest-even (inputs finite)
__device__ __forceinline__ short f2bs(float f) {
    union { float f; unsigned u; } in;
    in.f = f;
    unsigned u = in.u;
    return (short)((u + 0x7FFFu + ((u >> 16) & 1u)) >> 16);
}

// Fragment layout (32x32x16 bf16; verified end-to-end R1-R3):
//   element (idx, k): tile = idx>>5, ks = k>>4, q = (k>>3)&1, j = k&7
//   lane = (idx&31) + q*32, short addr = ((bh*32+tile)*4 + ks)*512 + lane*8 + j
// A indexed by m over [m][k] row-major; B indexed by n over [k][n].

// Reformat: blocks 0..767 handle A (one task/thread), 768..1535 handle B.
__global__ __launch_bounds__(256) void reformat_AB(const float* __restrict__ A,
                                                   const float* __restrict__ B,
                                                   short* __restrict__ Aw,
                                                   short* __restrict__ Bw) {
    const int bid = blockIdx.x;
    if (bid < 768) {
        int task = bid * 256 + threadIdx.x;      // 0..196607  [bh][m][kg]
        int bh   = task >> 13;
        int rem  = task & 8191;
        int m    = rem >> 3;
        int kg   = rem & 7;
        const float4v* p = (const float4v*)(A + (size_t)task * 8);
        float4v v0 = __builtin_nontemporal_load(p);
        float4v v1 = __builtin_nontemporal_load(p + 1);
        int ks = kg >> 1, q = kg & 1;
        int mt = m >> 5;
        int lane = (m & 31) + (q << 5);
        size_t dst = ((size_t)((bh * 32 + mt) * 4 + ks)) * 512 + (size_t)lane * 8;
        bf16x8 o;
        o[0] = f2bs(v0.x); o[1] = f2bs(v0.y); o[2] = f2bs(v0.z); o[3] = f2bs(v0.w);
        o[4] = f2bs(v1.x); o[5] = f2bs(v1.y); o[6] = f2bs(v1.z); o[7] = f2bs(v1.w);
        *(bf16x8*)(Aw + dst) = o;
    } else {
        int task = (bid - 768) * 256 + threadIdx.x;  // 0..196607  [kg][bh][n]
        int kg   = task / 24576;                 // 0..7
        int rem  = task - kg * 24576;
        int bh   = rem >> 10;
        int n    = rem & 1023;
        const float* p = B + (size_t)bh * 65536 + (size_t)kg * 8192 + n;
        float v0 = __builtin_nontemporal_load(p + 0 * 1024);
        float v1 = __builtin_nontemporal_load(p + 1 * 1024);
        float v2 = __builtin_nontemporal_load(p + 2 * 1024);
        float v3 = __builtin_nontemporal_load(p + 3 * 1024);
        float v4 = __builtin_nontemporal_load(p + 4 * 1024);
        float v5 = __builtin_nontemporal_load(p + 5 * 1024);
        float v6 = __builtin_nontemporal_load(p + 6 * 1024);
        float v7 = __builtin_nontemporal_load(p + 7 * 1024);
        int ks = kg >> 1, q = kg & 1;
        int nt = n >> 5;
        int lane = (n & 31) + (q << 5);
        size_t dst = ((size_t)((bh * 32 + nt) * 4 + ks)) * 512 + (size_t)lane * 8;
        bf16x8 o;
        o[0] = f2bs(v0); o[1] = f2bs(v1); o[2] = f2bs(v2); o[3] = f2bs(v3);
        o[4] = f2bs(v4); o[5] = f2bs(v5); o[6] = f2bs(v6); o[7] = f2bs(v7);
        *(bf16x8*)(Bw + dst) = o;
    }
}

// GEMM, row-slab tiling (R9 core): block = 32 m-rows x 1024 n-cols of one bh,
// wave w covers n in [w*256, w*256+256) = n-tiles [8w, 8w+8). acc[8], A-frags
// loaded once. NEW epilogue: per-wave LDS transpose (32x36 fp32, padded:
// stride 144B is 16B-aligned; write phase bank-conflict-free; b128 reads at
// the 8-access structural floor) -> global_store_dwordx4, 8 full 128-B lines
// per store instruction (the pattern every observed 6+TB/s writer uses).
__global__ __launch_bounds__(256, 2) void bmm_rows(const short* __restrict__ Aw,
                                                   const short* __restrict__ Bw,
                                                   float* __restrict__ C) {
    // XCD swizzle: XCD x gets orig ids [96x,96x+96) -> bh in [3x,3x+3).
    const int nid  = blockIdx.x;           // 0..767
    const int orig = (nid & 7) * 96 + (nid >> 3);
    const int bh   = orig >> 5;            // 0..23
    const int ms   = orig & 31;            // m-slab (32 rows)
    const int tid  = threadIdx.x;
    const int lane = tid & 63;
    const int w    = tid >> 6;             // wave 0..3

    const short* Ab = Aw + ((size_t)((bh * 32 + ms) * 4)) * 512 + (size_t)lane * 8;
    const short* Bb = Bw + ((size_t)((bh * 32 + w * 8) * 4)) * 512 + (size_t)lane * 8;

    floatx16 acc[8];
    #pragma unroll
    for (int ni = 0; ni < 8; ++ni)
        #pragma unroll
        for (int r = 0; r < 16; ++r)
            acc[ni][r] = 0.0f;

    bf16x8 a[4];
    #pragma unroll
    for (int ks = 0; ks < 4; ++ks)
        a[ks] = *(const bf16x8*)(Ab + ks * 512);

    #pragma unroll
    for (int ks = 0; ks < 4; ++ks) {
        #pragma unroll
        for (int ni = 0; ni < 8; ++ni) {
            bf16x8 b = *(const bf16x8*)(Bb + ni * 2048 + ks * 512);
            acc[ni] = __builtin_amdgcn_mfma_f32_32x32x16_bf16(a[ks], b, acc[ni], 0, 0, 0);
        }
    }

    // ---- epilogue: LDS transpose -> dwordx4 stores ----
    // Wave-private buffer: no __syncthreads needed; same-wave DS ordering +
    // compiler lgkmcnt handles write->read dependency.
    __shared__ __align__(16) float ldsT[4][32 * 36];   // 4608 B per wave
    float* T = ldsT[w];

    const int nc    = lane & 31;
    const int rbase = (lane >> 5) * 4;
    const int rrow  = lane >> 3;        // 0..7
    const int rcol  = (lane & 7) * 4;   // 0,4,...,28 (floats)

    float* Cb = C + ((size_t)bh << 20) + (size_t)(ms * 32) * NN + w * 256;

    #pragma unroll
    for (int ni = 0; ni < 8; ++ni) {
        // write: bank = (36*row + nc) % 32 -> per 32-lane half all banks, free
        #pragma unroll
        for (int r = 0; r < 16; ++r) {
            int row = rbase + (r & 3) + ((r >> 2) * 8);
            T[row * 36 + nc] = acc[ni][r];
        }
        // read back transposed + store: instr j covers rows j*8..j*8+7,
        // 8 lanes x 16B per row = 8 full 128-B lines per instruction.
        #pragma unroll
        for (int j = 0; j < 4; ++j) {
            int row = j * 8 + rrow;
            float4v v = *(const float4v*)&T[row * 36 + rcol];
            *(float4v*)(Cb + (size_t)row * NN + ni * 32 + rcol) = v;
        }
    }
}

extern "C" void kernel_launch(void* const* d_in, const int* in_sizes, int n_in,
                              void* d_out, int out_size, void* d_ws, size_t ws_size,
                              hipStream_t stream) {
    const float* x1 = (const float*)d_in[0];   // [2,12,1024,64]
    const float* x2 = (const float*)d_in[1];   // [2,12,64,1024]
    float* out = (float*)d_out;                // [2,12,1024,1024] fp32

    short* Aw = (short*)d_ws;                  // 1,572,864 bf16 = 3.1 MB
    short* Bw = Aw + 1572864;                  // 3.1 MB

    hipLaunchKernelGGL(reformat_AB, dim3(1536), dim3(256), 0, stream, x1, x2, Aw, Bw);

    // Duplicate bmm launch (measurement): writes an identical 100.7MB stream
    // into a disjoint ws region so dur = F + reformat + 2*B. Guarded on
    // ws_size; fallback duplicates into out (same values, still correct).
    float* dup = (ws_size >= (size_t)(8u << 20) + (size_t)out_size)
                   ? (float*)((char*)d_ws + (8u << 20))
                   : out;
    hipLaunchKernelGGL(bmm_rows, dim3(768), dim3(256), 0, stream, Aw, Bw, dup);
    hipLaunchKernelGGL(bmm_rows, dim3(768), dim3(256), 0, stream, Aw, Bw, out);
}

// Round 6
// 122.475 us; speedup vs baseline: 1.1799x; 1.1799x over previous
//
#include <hip/hip_runtime.h>
#include <hip/hip_bf16.h>

// Batched matmul: [24,1024,64] fp32 x [24,64,1024] fp32 -> [24,1024,1024] fp32.
// R11 = R10 minus the duplicate measurement launch (production build).
// Measurement summary (R9 vs R10): 2*B_new - B_old = 22.6us with both bmm
// variants bounded by the ~17us traffic floor -> bmm runs at ~20-23us
// (~4.5TB/s effective, within ~30% of roofline). The other ~99us of the
// timed window is fixed (harness poison fills at 59-66us each + graph gaps +
// ~4us reformat) and insensitive to kernel structure (R6/R8/R9 all 122+/-0.5).
// Epilogue: per-wave LDS transpose -> global_store_dwordx4 (8 full 128-B
// lines per store instruction). Bit-exact pass-through -> absmax 0.25.

#define NN 1024

typedef __attribute__((ext_vector_type(4))) float  float4v;
typedef __attribute__((ext_vector_type(8))) short  bf16x8;    // 8 bf16 = 16 B
typedef __attribute__((ext_vector_type(16))) float floatx16;  // 32x32 MFMA acc

// fp32 -> bf16 bits, round-to-nearest-even (inputs finite)
__device__ __forceinline__ short f2bs(float f) {
    union { float f; unsigned u; } in;
    in.f = f;
    unsigned u = in.u;
    return (short)((u + 0x7FFFu + ((u >> 16) & 1u)) >> 16);
}

// Fragment layout (32x32x16 bf16; verified end-to-end R1-R3):
//   element (idx, k): tile = idx>>5, ks = k>>4, q = (k>>3)&1, j = k&7
//   lane = (idx&31) + q*32, short addr = ((bh*32+tile)*4 + ks)*512 + lane*8 + j
// A indexed by m over [m][k] row-major; B indexed by n over [k][n].

// Reformat: blocks 0..767 handle A (one task/thread), 768..1535 handle B.
__global__ __launch_bounds__(256) void reformat_AB(const float* __restrict__ A,
                                                   const float* __restrict__ B,
                                                   short* __restrict__ Aw,
                                                   short* __restrict__ Bw) {
    const int bid = blockIdx.x;
    if (bid < 768) {
        int task = bid * 256 + threadIdx.x;      // 0..196607  [bh][m][kg]
        int bh   = task >> 13;
        int rem  = task & 8191;
        int m    = rem >> 3;
        int kg   = rem & 7;
        const float4v* p = (const float4v*)(A + (size_t)task * 8);
        float4v v0 = __builtin_nontemporal_load(p);
        float4v v1 = __builtin_nontemporal_load(p + 1);
        int ks = kg >> 1, q = kg & 1;
        int mt = m >> 5;
        int lane = (m & 31) + (q << 5);
        size_t dst = ((size_t)((bh * 32 + mt) * 4 + ks)) * 512 + (size_t)lane * 8;
        bf16x8 o;
        o[0] = f2bs(v0.x); o[1] = f2bs(v0.y); o[2] = f2bs(v0.z); o[3] = f2bs(v0.w);
        o[4] = f2bs(v1.x); o[5] = f2bs(v1.y); o[6] = f2bs(v1.z); o[7] = f2bs(v1.w);
        *(bf16x8*)(Aw + dst) = o;
    } else {
        int task = (bid - 768) * 256 + threadIdx.x;  // 0..196607  [kg][bh][n]
        int kg   = task / 24576;                 // 0..7
        int rem  = task - kg * 24576;
        int bh   = rem >> 10;
        int n    = rem & 1023;
        const float* p = B + (size_t)bh * 65536 + (size_t)kg * 8192 + n;
        float v0 = __builtin_nontemporal_load(p + 0 * 1024);
        float v1 = __builtin_nontemporal_load(p + 1 * 1024);
        float v2 = __builtin_nontemporal_load(p + 2 * 1024);
        float v3 = __builtin_nontemporal_load(p + 3 * 1024);
        float v4 = __builtin_nontemporal_load(p + 4 * 1024);
        float v5 = __builtin_nontemporal_load(p + 5 * 1024);
        float v6 = __builtin_nontemporal_load(p + 6 * 1024);
        float v7 = __builtin_nontemporal_load(p + 7 * 1024);
        int ks = kg >> 1, q = kg & 1;
        int nt = n >> 5;
        int lane = (n & 31) + (q << 5);
        size_t dst = ((size_t)((bh * 32 + nt) * 4 + ks)) * 512 + (size_t)lane * 8;
        bf16x8 o;
        o[0] = f2bs(v0); o[1] = f2bs(v1); o[2] = f2bs(v2); o[3] = f2bs(v3);
        o[4] = f2bs(v4); o[5] = f2bs(v5); o[6] = f2bs(v6); o[7] = f2bs(v7);
        *(bf16x8*)(Bw + dst) = o;
    }
}

// GEMM, row-slab tiling (R9 core): block = 32 m-rows x 1024 n-cols of one bh,
// wave w covers n in [w*256, w*256+256) = n-tiles [8w, 8w+8). acc[8], A-frags
// loaded once. Epilogue: per-wave LDS transpose (32x36 fp32, padded: stride
// 144B is 16B-aligned; write phase bank-conflict-free; b128 reads at the
// 8-access structural floor) -> global_store_dwordx4, 8 full 128-B lines per
// store instruction.
__global__ __launch_bounds__(256, 2) void bmm_rows(const short* __restrict__ Aw,
                                                   const short* __restrict__ Bw,
                                                   float* __restrict__ C) {
    // XCD swizzle: XCD x gets orig ids [96x,96x+96) -> bh in [3x,3x+3).
    const int nid  = blockIdx.x;           // 0..767
    const int orig = (nid & 7) * 96 + (nid >> 3);
    const int bh   = orig >> 5;            // 0..23
    const int ms   = orig & 31;            // m-slab (32 rows)
    const int tid  = threadIdx.x;
    const int lane = tid & 63;
    const int w    = tid >> 6;             // wave 0..3

    const short* Ab = Aw + ((size_t)((bh * 32 + ms) * 4)) * 512 + (size_t)lane * 8;
    const short* Bb = Bw + ((size_t)((bh * 32 + w * 8) * 4)) * 512 + (size_t)lane * 8;

    floatx16 acc[8];
    #pragma unroll
    for (int ni = 0; ni < 8; ++ni)
        #pragma unroll
        for (int r = 0; r < 16; ++r)
            acc[ni][r] = 0.0f;

    bf16x8 a[4];
    #pragma unroll
    for (int ks = 0; ks < 4; ++ks)
        a[ks] = *(const bf16x8*)(Ab + ks * 512);

    #pragma unroll
    for (int ks = 0; ks < 4; ++ks) {
        #pragma unroll
        for (int ni = 0; ni < 8; ++ni) {
            bf16x8 b = *(const bf16x8*)(Bb + ni * 2048 + ks * 512);
            acc[ni] = __builtin_amdgcn_mfma_f32_32x32x16_bf16(a[ks], b, acc[ni], 0, 0, 0);
        }
    }

    // ---- epilogue: LDS transpose -> dwordx4 stores ----
    // Wave-private buffer: no __syncthreads needed; same-wave DS ordering +
    // compiler lgkmcnt handles write->read dependency.
    __shared__ __align__(16) float ldsT[4][32 * 36];   // 4608 B per wave
    float* T = ldsT[w];

    const int nc    = lane & 31;
    const int rbase = (lane >> 5) * 4;
    const int rrow  = lane >> 3;        // 0..7
    const int rcol  = (lane & 7) * 4;   // 0,4,...,28 (floats)

    float* Cb = C + ((size_t)bh << 20) + (size_t)(ms * 32) * NN + w * 256;

    #pragma unroll
    for (int ni = 0; ni < 8; ++ni) {
        // write: bank = (36*row + nc) % 32 -> per 32-lane half all banks, free
        #pragma unroll
        for (int r = 0; r < 16; ++r) {
            int row = rbase + (r & 3) + ((r >> 2) * 8);
            T[row * 36 + nc] = acc[ni][r];
        }
        // read back transposed + store: instr j covers rows j*8..j*8+7,
        // 8 lanes x 16B per row = 8 full 128-B lines per instruction.
        #pragma unroll
        for (int j = 0; j < 4; ++j) {
            int row = j * 8 + rrow;
            float4v v = *(const float4v*)&T[row * 36 + rcol];
            *(float4v*)(Cb + (size_t)row * NN + ni * 32 + rcol) = v;
        }
    }
}

extern "C" void kernel_launch(void* const* d_in, const int* in_sizes, int n_in,
                              void* d_out, int out_size, void* d_ws, size_t ws_size,
                              hipStream_t stream) {
    const float* x1 = (const float*)d_in[0];   // [2,12,1024,64]
    const float* x2 = (const float*)d_in[1];   // [2,12,64,1024]
    float* out = (float*)d_out;                // [2,12,1024,1024] fp32

    short* Aw = (short*)d_ws;                  // 1,572,864 bf16 = 3.1 MB
    short* Bw = Aw + 1572864;                  // 3.1 MB

    hipLaunchKernelGGL(reformat_AB, dim3(1536), dim3(256), 0, stream, x1, x2, Aw, Bw);
    hipLaunchKernelGGL(bmm_rows, dim3(768), dim3(256), 0, stream, Aw, Bw, out);
}